// Round 10
// baseline (665.504 us; speedup 1.0000x reference)
//
#include <hip/hip_runtime.h>

#define M_DIM 16384   // 8 * 2048
#define N_DIM 4096
#define K_DIM 4096
#define BK 64
#define NKT (K_DIM / BK)   // 64 K-tiles

typedef unsigned char u8;
typedef __attribute__((ext_vector_type(4))) int   i32x4;

#define AS1 __attribute__((address_space(1)))
#define AS3 __attribute__((address_space(3)))

// ---- prepass: per-row symmetric quant of A to i8, plus row scale & rowsum ----
__global__ __launch_bounds__(256)
void quant_a_kernel(const float* __restrict__ in, char* __restrict__ out,
                    float* __restrict__ srow, int* __restrict__ rsum) {
    const int row  = blockIdx.x;
    const int t    = threadIdx.x;
    const int lane = t & 63, wv = t >> 6;
    const float4* rp = (const float4*)(in + (size_t)row * K_DIM);

    float4 v[4];
#pragma unroll
    for (int j = 0; j < 4; ++j) v[j] = rp[t + 256 * j];

    float amax = 0.f;
#pragma unroll
    for (int j = 0; j < 4; ++j) {
        amax = fmaxf(amax, fmaxf(fmaxf(fabsf(v[j].x), fabsf(v[j].y)),
                                 fmaxf(fabsf(v[j].z), fabsf(v[j].w))));
    }
#pragma unroll
    for (int off = 32; off; off >>= 1) amax = fmaxf(amax, __shfl_xor(amax, off));
    __shared__ float wred[4];
    __shared__ int   sred[4];
    if (lane == 0) wred[wv] = amax;
    __syncthreads();
    amax = fmaxf(fmaxf(wred[0], wred[1]), fmaxf(wred[2], wred[3]));
    const float inv = amax > 0.f ? 127.f / amax : 0.f;

    int lsum = 0;
    unsigned* orow = (unsigned*)(out + (size_t)row * K_DIM);
#pragma unroll
    for (int j = 0; j < 4; ++j) {
        int q0 = __float2int_rn(v[j].x * inv);
        int q1 = __float2int_rn(v[j].y * inv);
        int q2 = __float2int_rn(v[j].z * inv);
        int q3 = __float2int_rn(v[j].w * inv);
        lsum += q0 + q1 + q2 + q3;
        unsigned pk = (unsigned)(q0 & 0xFF) | ((unsigned)(q1 & 0xFF) << 8) |
                      ((unsigned)(q2 & 0xFF) << 16) | ((unsigned)(q3 & 0xFF) << 24);
        orow[t + 256 * j] = pk;
    }
#pragma unroll
    for (int off = 32; off; off >>= 1) lsum += __shfl_xor(lsum, off);
    if (lane == 0) sred[wv] = lsum;
    __syncthreads();
    if (t == 0) {
        rsum[row] = sred[0] + sred[1] + sred[2] + sred[3];
        srow[row] = amax > 0.f ? amax / 127.f : 1.f;
    }
}

// ---- prepass: W int32 -> raw i8 pack (no dequant; zp corrected in epilogue) ----
__global__ __launch_bounds__(256)
void pack_w_kernel(const int* __restrict__ q, char* __restrict__ out, int n4) {
    int stride = gridDim.x * blockDim.x;
    for (int i = blockIdx.x * blockDim.x + threadIdx.x; i < n4; i += stride) {
        int4 a = ((const int4*)q)[i];
        unsigned pk = (unsigned)(a.x & 0xFF) | ((unsigned)(a.y & 0xFF) << 8) |
                      ((unsigned)(a.z & 0xFF) << 16) | ((unsigned)(a.w & 0xFF) << 24);
        ((unsigned*)out)[i] = pk;
    }
}

// ---- 128x256 i8 GEMM: A direct-from-global (L1-served), B-only LDS ring-4 ----
// 256 thr = 4 waves, all at wr=0: per-wave out 128x64 (acc i32x4[8][4]).
// All waves read the SAME A rows -> A frag loads (8 global_load_dwordx4/tile)
// are L1 hits after the first wave; LDS holds only B (ring-4 x 16 KB = 64 KiB
// -> 2 blocks/CU, cross-block desync fills the MFMA pipe; B dup = 1x ->
// LDS reads just 16/tile/block). Swizzle identical involution to R5:
// write slot (l&3) <- source slot (l&3)^((l>>3)&3); read koff ^(row>>1)&3.
// vmcnt ledger: A(u) loads drained by compiler auto-waits before MFMA
// (stage(u+3) = newest 4 stays in flight); tile-end vmcnt(8) counts only
// stages u+1..u+3 (12) -> drains u+1; tails 4 -> 0.
__global__ __launch_bounds__(256, 2)
void gemm_i8_kernel(const char* __restrict__ A, const char* __restrict__ B,
                    const float* __restrict__ srow, const int* __restrict__ rsum,
                    const float* __restrict__ wsc_p, const int* __restrict__ wzp_p,
                    const int* __restrict__ qb, const float* __restrict__ bsc_p,
                    const int* __restrict__ bzp_p, float* __restrict__ C) {
    __shared__ __align__(16) u8 ldsB[4 * 16384];   // 64 KiB

    // XCD-bijective swizzle + 8(bm)x4(bn) supertiles (nwg=2048, %8==0)
    const int nwg = gridDim.x;
    const int cpx = nwg >> 3;                 // 256
    const int bid = blockIdx.x;
    const int swz = (bid & 7) * cpx + (bid >> 3);
    const int st = swz >> 5, wi = swz & 31;   // 64 supertiles of 8x4
    const int bm = (st >> 2) * 8 + (wi >> 2); // 0..127
    const int bn = (st & 3) * 4 + (wi & 3);   // 0..15
    const int m0 = bm * 128, n0 = bn * 256;

    const int tid  = threadIdx.x;
    const int wv   = tid >> 6;    // 0..3 = wave col (64 N-cols each)
    const int lane = tid & 63;
    const int l15  = lane & 15;

    // read-side swizzled k-slot byte offset (row%16 == l15)
    const int koff = (((lane >> 4) ^ ((lane >> 1) & 3)) << 4);

    // B staging: per wave 4 loads/tile; dst = ns*16384 + i*4096 + wv*1024
    // (+lane*16 implicit); src row = i*64 + wv*16 + (lane>>2), col pre-swizzled.
    const int srow_ = wv * 16 + (lane >> 2);
    const int gcol  = (((lane & 3) ^ ((lane >> 3) & 3)) << 4);
    const char* BgT = B + (size_t)(n0 + srow_) * K_DIM + gcol;
    const int wvo = wv << 10;

    // A direct: af[mi] lane addr = A + (m0 + mi*16 + l15)*K + u*64 + (lane>>4)*16
    const char* Ag = A + (size_t)(m0 + l15) * K_DIM + ((lane >> 4) << 4);

    i32x4 acc[8][4] = {};

    auto STAGE_B = [&](int ns, int k3) {
#pragma unroll
        for (int i = 0; i < 4; ++i)
            __builtin_amdgcn_global_load_lds(
                (const AS1 void*)(BgT + (size_t)i * 64 * K_DIM + k3),
                (AS3 void*)(ldsB + ns * 16384 + i * 4096 + wvo), 16, 0, 0);
    };

    // ---- prologue: stage B K-tiles 0,1,2 (12 loads/wave) ----
    STAGE_B(0, 0);
    STAGE_B(1, BK);
    STAGE_B(2, 2 * BK);
    asm volatile("s_waitcnt vmcnt(8)" ::: "memory");   // B tile 0 landed
    __builtin_amdgcn_s_barrier();
    __builtin_amdgcn_sched_barrier(0);

    for (int u = 0; u < NKT; ++u) {
        const u8* Bsl = ldsB + (u & 3) * 16384;
        const int k0 = u * BK;

        // A fragments direct from global (L1-served after first wave)
        i32x4 af[8];
#pragma unroll
        for (int mi = 0; mi < 8; ++mi)
            af[mi] = *(const i32x4*)(Ag + (size_t)(mi * 16) * K_DIM + k0);

        // B fragments from swizzled LDS (4 reads, dup 1x)
        i32x4 bfr[4];
#pragma unroll
        for (int ni = 0; ni < 4; ++ni)
            bfr[ni] = *(const i32x4*)(Bsl + (wv * 64 + ni * 16 + l15) * 64 + koff);

        // stage B(u+3) into slot of tile u-1 (reads retired pre-barrier)
        if (u + 3 < NKT) STAGE_B((u + 3) & 3, (u + 3) * BK);

        // MFMAs: compiler auto-inserts vmcnt/lgkm waits for af/bfr deps
        __builtin_amdgcn_s_setprio(1);
#pragma unroll
        for (int mi = 0; mi < 8; ++mi)
#pragma unroll
            for (int ni = 0; ni < 4; ++ni)
                acc[mi][ni] = __builtin_amdgcn_mfma_i32_16x16x64_i8(
                    af[mi], bfr[ni], acc[mi][ni], 0, 0, 0);
        __builtin_amdgcn_s_setprio(0);

        // tile end: bfr retired (data-dep); counted vmcnt for stage(u+1)
        asm volatile("s_waitcnt lgkmcnt(0)" ::: "memory");
        if (u < NKT - 3)       asm volatile("s_waitcnt vmcnt(8)" ::: "memory");
        else if (u == NKT - 3) asm volatile("s_waitcnt vmcnt(4)" ::: "memory");
        else if (u == NKT - 2) asm volatile("s_waitcnt vmcnt(0)" ::: "memory");
        __builtin_amdgcn_s_barrier();
        __builtin_amdgcn_sched_barrier(0);
    }

    // ---- epilogue: dequant + zp correction + bias ----
    const float ws  = wsc_p[0];
    const float zpf = (float)wzp_p[0];
    const float bsc = bsc_p[0];
    const float bzp = (float)bzp_p[0];
    float bias_[4];
#pragma unroll
    for (int ni = 0; ni < 4; ++ni) {
        int col = n0 + wv * 64 + ni * 16 + l15;
        bias_[ni] = ((float)qb[col] - bzp) * bsc;
    }
#pragma unroll
    for (int mi = 0; mi < 8; ++mi) {
        int rbase = m0 + mi * 16 + (lane >> 4) * 4;
        float fs_[4], fc_[4];
#pragma unroll
        for (int i = 0; i < 4; ++i) {
            float sf = ws * srow[rbase + i];
            fs_[i] = sf;
            fc_[i] = -sf * zpf * (float)rsum[rbase + i];
        }
#pragma unroll
        for (int ni = 0; ni < 4; ++ni) {
            int col = n0 + wv * 64 + ni * 16 + l15;
#pragma unroll
            for (int i = 0; i < 4; ++i)
                C[(size_t)(rbase + i) * N_DIM + col] =
                    fs_[i] * (float)acc[mi][ni][i] + fc_[i] + bias_[ni];
        }
    }
}

// ---- fallback (only if ws too small): correct, slow ----
__global__ void gemm_fallback_kernel(const float* __restrict__ A, const int* __restrict__ Wq,
                                     const float* __restrict__ wsc_p, const int* __restrict__ wzp_p,
                                     const int* __restrict__ qb, const float* __restrict__ bsc_p,
                                     const int* __restrict__ bzp_p, float* __restrict__ C) {
    int m = blockIdx.y;
    int n = blockIdx.x * 256 + threadIdx.x;
    float zp = (float)wzp_p[0];
    float sc = wsc_p[0];
    __shared__ float Arow[512];
    float acc = 0.f;
    for (int k0 = 0; k0 < K_DIM; k0 += 512) {
        __syncthreads();
        for (int t = threadIdx.x; t < 512; t += 256)
            Arow[t] = A[(size_t)m * K_DIM + k0 + t];
        __syncthreads();
        const int4* wp = (const int4*)(Wq + (size_t)n * K_DIM + k0);
        for (int kk = 0; kk < 512; kk += 4) {
            int4 q = wp[kk >> 2];
            acc += Arow[kk]     * ((float)q.x - zp);
            acc += Arow[kk + 1] * ((float)q.y - zp);
            acc += Arow[kk + 2] * ((float)q.z - zp);
            acc += Arow[kk + 3] * ((float)q.w - zp);
        }
    }
    acc *= sc;
    acc += ((float)qb[n] - (float)bzp_p[0]) * bsc_p[0];
    C[(size_t)m * N_DIM + n] = acc;
}

extern "C" void kernel_launch(void* const* d_in, const int* in_sizes, int n_in,
                              void* d_out, int out_size, void* d_ws, size_t ws_size,
                              hipStream_t stream) {
    (void)in_sizes; (void)n_in; (void)out_size;
    const float* input = (const float*)d_in[0];
    const int*   qw    = (const int*)d_in[1];
    const float* wsc   = (const float*)d_in[2];
    const int*   wzp   = (const int*)d_in[3];
    const int*   qb    = (const int*)d_in[4];
    const float* bsc   = (const float*)d_in[5];
    const int*   bzp   = (const int*)d_in[6];
    float* out = (float*)d_out;

    size_t offA = 0;
    size_t offW = (size_t)M_DIM * K_DIM;                 // 64 MB (i8)
    size_t offS = offW + (size_t)N_DIM * K_DIM;          // +16 MB
    size_t offR = offS + (size_t)M_DIM * sizeof(float);  // +64 KB
    size_t need = offR + (size_t)M_DIM * sizeof(int);    // ~80.1 MB

    if (ws_size >= need) {
        char*  Aq = (char*)d_ws + offA;
        char*  Wq8 = (char*)d_ws + offW;
        float* S  = (float*)((char*)d_ws + offS);
        int*   R  = (int*)((char*)d_ws + offR);
        quant_a_kernel<<<M_DIM, 256, 0, stream>>>(input, Aq, S, R);
        pack_w_kernel<<<2048, 256, 0, stream>>>(qw, Wq8, N_DIM * K_DIM / 4);
        gemm_i8_kernel<<<(M_DIM / 128) * (N_DIM / 256), 256, 0, stream>>>(
            Aq, Wq8, S, R, wsc, wzp, qb, bsc, bzp, out);
    } else {
        dim3 grid(N_DIM / 256, M_DIM);
        gemm_fallback_kernel<<<grid, 256, 0, stream>>>(input, qw, wsc, wzp, qb, bsc, bzp, out);
    }
}

// Round 11
// 413.520 us; speedup vs baseline: 1.6094x; 1.6094x over previous
//
#include <hip/hip_runtime.h>

#define M_DIM 16384   // 8 * 2048
#define N_DIM 4096
#define K_DIM 4096
#define BK 64
#define NKT (K_DIM / BK)   // 64 K-tiles

typedef unsigned char u8;
typedef __attribute__((ext_vector_type(4))) int   i32x4;

// ---- prepass: per-row symmetric quant of A to i8, packed FRAGMENT-MAJOR ----
// A'[mt][kt][lane][16B]: mt=row/16, kt=k/64, lane=(k%64)/16*16 + row%16.
// One block per row; thread t owns 16 consecutive floats (bytes 16t..16t+15).
__global__ __launch_bounds__(256)
void quant_a_kernel(const float* __restrict__ in, char* __restrict__ out,
                    float* __restrict__ srow, int* __restrict__ rsum) {
    const int row  = blockIdx.x;
    const int t    = threadIdx.x;
    const int lane = t & 63, wv = t >> 6;
    const float4* rp = (const float4*)(in + (size_t)row * K_DIM);

    float4 v[4];
#pragma unroll
    for (int j = 0; j < 4; ++j) v[j] = rp[t * 4 + j];   // 16 consecutive floats

    float amax = 0.f;
#pragma unroll
    for (int j = 0; j < 4; ++j) {
        amax = fmaxf(amax, fmaxf(fmaxf(fabsf(v[j].x), fabsf(v[j].y)),
                                 fmaxf(fabsf(v[j].z), fabsf(v[j].w))));
    }
#pragma unroll
    for (int off = 32; off; off >>= 1) amax = fmaxf(amax, __shfl_xor(amax, off));
    __shared__ float wred[4];
    __shared__ int   sred[4];
    if (lane == 0) wred[wv] = amax;
    __syncthreads();
    amax = fmaxf(fmaxf(wred[0], wred[1]), fmaxf(wred[2], wred[3]));
    const float inv = amax > 0.f ? 127.f / amax : 0.f;

    int lsum = 0;
    int pk[4];
#pragma unroll
    for (int j = 0; j < 4; ++j) {
        int q0 = __float2int_rn(v[j].x * inv);
        int q1 = __float2int_rn(v[j].y * inv);
        int q2 = __float2int_rn(v[j].z * inv);
        int q3 = __float2int_rn(v[j].w * inv);
        lsum += q0 + q1 + q2 + q3;
        pk[j] = (int)((unsigned)(q0 & 0xFF) | ((unsigned)(q1 & 0xFF) << 8) |
                      ((unsigned)(q2 & 0xFF) << 16) | ((unsigned)(q3 & 0xFF) << 24));
    }
    // fragment-major dest: chunk c = t; kt = c>>2, j = c&3, flane = j*16 + row%16
    {
        const int mt = row >> 4, r = row & 15;
        const int kt = t >> 2,  j = t & 3;
        const size_t off = ((size_t)mt * NKT + kt) * 1024 + (size_t)(j * 16 + r) * 16;
        i32x4 w; w[0] = pk[0]; w[1] = pk[1]; w[2] = pk[2]; w[3] = pk[3];
        *(i32x4*)(out + off) = w;
    }
#pragma unroll
    for (int off = 32; off; off >>= 1) lsum += __shfl_xor(lsum, off);
    if (lane == 0) sred[wv] = lsum;
    __syncthreads();
    if (t == 0) {
        rsum[row] = sred[0] + sred[1] + sred[2] + sred[3];
        srow[row] = amax > 0.f ? amax / 127.f : 1.f;
    }
}

// ---- prepass: W int32 -> i8, packed FRAGMENT-MAJOR (same layout as A') ----
// One block per output row o; thread t owns 16 consecutive int32 -> 16 bytes.
__global__ __launch_bounds__(256)
void pack_w_kernel(const int* __restrict__ q, char* __restrict__ out) {
    const int o = blockIdx.x;
    const int t = threadIdx.x;
    const int4* qp = (const int4*)(q + (size_t)o * K_DIM);
    int pk[4];
#pragma unroll
    for (int j = 0; j < 4; ++j) {
        int4 a = qp[t * 4 + j];
        pk[j] = (int)((unsigned)(a.x & 0xFF) | ((unsigned)(a.y & 0xFF) << 8) |
                      ((unsigned)(a.z & 0xFF) << 16) | ((unsigned)(a.w & 0xFF) << 24));
    }
    const int nt = o >> 4, r = o & 15;
    const int kt = t >> 2, j = t & 3;
    const size_t off = ((size_t)nt * NKT + kt) * 1024 + (size_t)(j * 16 + r) * 16;
    i32x4 w; w[0] = pk[0]; w[1] = pk[1]; w[2] = pk[2]; w[3] = pk[3];
    *(i32x4*)(out + off) = w;
}

// ---- 128x256 i8 GEMM: ZERO LDS, ZERO barriers — both operands read from
// fragment-major packed global (each frag load = one coalesced 1KB line).
// 256 thr = 4 waves (each one 64-col slice); all waves read identical A
// fragments -> L1 broadcast; B panels L2-resident via supertile swizzle.
// No sync at all: compiler pipelines loads across iterations; 2 blocks/CU
// (LDS=0, ~80 arch VGPR + 128 AGPR acc = fits 2 waves/SIMD) provide the
// desynchronized co-tenant that hides VMEM latency under MFMA.
__global__ __launch_bounds__(256, 2)
void gemm_i8_kernel(const char* __restrict__ Ap, const char* __restrict__ Wp,
                    const float* __restrict__ srow, const int* __restrict__ rsum,
                    const float* __restrict__ wsc_p, const int* __restrict__ wzp_p,
                    const int* __restrict__ qb, const float* __restrict__ bsc_p,
                    const int* __restrict__ bzp_p, float* __restrict__ C) {
    // XCD-bijective swizzle + 8(bm)x4(bn) supertiles (nwg=2048, %8==0)
    const int nwg = gridDim.x;
    const int cpx = nwg >> 3;                 // 256
    const int bid = blockIdx.x;
    const int swz = (bid & 7) * cpx + (bid >> 3);
    const int st = swz >> 5, wi = swz & 31;   // 64 supertiles of 8x4
    const int bm = (st >> 2) * 8 + (wi >> 2); // 0..127
    const int bn = (st & 3) * 4 + (wi & 3);   // 0..15
    const int m0 = bm * 128, n0 = bn * 256;

    const int tid  = threadIdx.x;
    const int wv   = tid >> 6;    // 0..3 : wave col (64 N-cols each)
    const int lane = tid & 63;
    const int l15  = lane & 15;

    // fragment bases: lane*16 within each 1KB fragment block
    const char* Aft = Ap + ((size_t)(bm * 8) * NKT) * 1024 + lane * 16;
    const char* Wft = Wp + ((size_t)(bn * 16 + wv * 4) * NKT) * 1024 + lane * 16;

    i32x4 acc[8][4] = {};

    for (int u = 0; u < NKT; ++u) {
        i32x4 af[8], bfr[4];
#pragma unroll
        for (int mi = 0; mi < 8; ++mi)
            af[mi] = *(const i32x4*)(Aft + ((size_t)mi * NKT + u) * 1024);
#pragma unroll
        for (int ni = 0; ni < 4; ++ni)
            bfr[ni] = *(const i32x4*)(Wft + ((size_t)ni * NKT + u) * 1024);

        __builtin_amdgcn_s_setprio(1);
#pragma unroll
        for (int mi = 0; mi < 8; ++mi)
#pragma unroll
            for (int ni = 0; ni < 4; ++ni)
                acc[mi][ni] = __builtin_amdgcn_mfma_i32_16x16x64_i8(
                    af[mi], bfr[ni], acc[mi][ni], 0, 0, 0);
        __builtin_amdgcn_s_setprio(0);
    }

    // ---- epilogue: dequant + zp correction + bias ----
    const float ws  = wsc_p[0];
    const float zpf = (float)wzp_p[0];
    const float bsc = bsc_p[0];
    const float bzp = (float)bzp_p[0];
    float bias_[4];
#pragma unroll
    for (int ni = 0; ni < 4; ++ni) {
        int col = n0 + wv * 64 + ni * 16 + l15;
        bias_[ni] = ((float)qb[col] - bzp) * bsc;
    }
#pragma unroll
    for (int mi = 0; mi < 8; ++mi) {
        int rbase = m0 + mi * 16 + (lane >> 4) * 4;
        float fs_[4], fc_[4];
#pragma unroll
        for (int i = 0; i < 4; ++i) {
            float sf = ws * srow[rbase + i];
            fs_[i] = sf;
            fc_[i] = -sf * zpf * (float)rsum[rbase + i];
        }
#pragma unroll
        for (int ni = 0; ni < 4; ++ni) {
            int col = n0 + wv * 64 + ni * 16 + l15;
#pragma unroll
            for (int i = 0; i < 4; ++i)
                C[(size_t)(rbase + i) * N_DIM + col] =
                    fs_[i] * (float)acc[mi][ni][i] + fc_[i] + bias_[ni];
        }
    }
}

// ---- fallback (only if ws too small): correct, slow ----
__global__ void gemm_fallback_kernel(const float* __restrict__ A, const int* __restrict__ Wq,
                                     const float* __restrict__ wsc_p, const int* __restrict__ wzp_p,
                                     const int* __restrict__ qb, const float* __restrict__ bsc_p,
                                     const int* __restrict__ bzp_p, float* __restrict__ C) {
    int m = blockIdx.y;
    int n = blockIdx.x * 256 + threadIdx.x;
    float zp = (float)wzp_p[0];
    float sc = wsc_p[0];
    __shared__ float Arow[512];
    float acc = 0.f;
    for (int k0 = 0; k0 < K_DIM; k0 += 512) {
        __syncthreads();
        for (int t = threadIdx.x; t < 512; t += 256)
            Arow[t] = A[(size_t)m * K_DIM + k0 + t];
        __syncthreads();
        const int4* wp = (const int4*)(Wq + (size_t)n * K_DIM + k0);
        for (int kk = 0; kk < 512; kk += 4) {
            int4 q = wp[kk >> 2];
            acc += Arow[kk]     * ((float)q.x - zp);
            acc += Arow[kk + 1] * ((float)q.y - zp);
            acc += Arow[kk + 2] * ((float)q.z - zp);
            acc += Arow[kk + 3] * ((float)q.w - zp);
        }
    }
    acc *= sc;
    acc += ((float)qb[n] - (float)bzp_p[0]) * bsc_p[0];
    C[(size_t)m * N_DIM + n] = acc;
}

extern "C" void kernel_launch(void* const* d_in, const int* in_sizes, int n_in,
                              void* d_out, int out_size, void* d_ws, size_t ws_size,
                              hipStream_t stream) {
    (void)in_sizes; (void)n_in; (void)out_size;
    const float* input = (const float*)d_in[0];
    const int*   qw    = (const int*)d_in[1];
    const float* wsc   = (const float*)d_in[2];
    const int*   wzp   = (const int*)d_in[3];
    const int*   qb    = (const int*)d_in[4];
    const float* bsc   = (const float*)d_in[5];
    const int*   bzp   = (const int*)d_in[6];
    float* out = (float*)d_out;

    size_t offA = 0;
    size_t offW = (size_t)M_DIM * K_DIM;                 // 64 MB (i8 packed)
    size_t offS = offW + (size_t)N_DIM * K_DIM;          // +16 MB
    size_t offR = offS + (size_t)M_DIM * sizeof(float);  // +64 KB
    size_t need = offR + (size_t)M_DIM * sizeof(int);    // ~80.1 MB

    if (ws_size >= need) {
        char*  Aq = (char*)d_ws + offA;
        char*  Wq8 = (char*)d_ws + offW;
        float* S  = (float*)((char*)d_ws + offS);
        int*   R  = (int*)((char*)d_ws + offR);
        quant_a_kernel<<<M_DIM, 256, 0, stream>>>(input, Aq, S, R);
        pack_w_kernel<<<N_DIM, 256, 0, stream>>>(qw, Wq8);
        gemm_i8_kernel<<<(M_DIM / 128) * (N_DIM / 256), 256, 0, stream>>>(
            Aq, Wq8, S, R, wsc, wzp, qb, bsc, bzp, out);
    } else {
        dim3 grid(N_DIM / 256, M_DIM);
        gemm_fallback_kernel<<<grid, 256, 0, stream>>>(input, qw, wsc, wzp, qb, bsc, bzp, out);
    }
}

// Round 12
// 390.411 us; speedup vs baseline: 1.7046x; 1.0592x over previous
//
#include <hip/hip_runtime.h>

#define M_DIM 16384   // 8 * 2048
#define N_DIM 4096
#define K_DIM 4096
#define BK 64
#define NKT (K_DIM / BK)   // 64 K-tiles

typedef unsigned char u8;
typedef __attribute__((ext_vector_type(4))) int   i32x4;

#define AS1 __attribute__((address_space(1)))
#define AS3 __attribute__((address_space(3)))

// ---- prepass: per-row symmetric quant of A to i8 (row-major, coalesced) ----
__global__ __launch_bounds__(256)
void quant_a_kernel(const float* __restrict__ in, char* __restrict__ out,
                    float* __restrict__ srow, int* __restrict__ rsum) {
    const int row  = blockIdx.x;
    const int t    = threadIdx.x;
    const int lane = t & 63, wv = t >> 6;
    const float4* rp = (const float4*)(in + (size_t)row * K_DIM);

    float4 v[4];
#pragma unroll
    for (int j = 0; j < 4; ++j) v[j] = rp[t + 256 * j];

    float amax = 0.f;
#pragma unroll
    for (int j = 0; j < 4; ++j) {
        amax = fmaxf(amax, fmaxf(fmaxf(fabsf(v[j].x), fabsf(v[j].y)),
                                 fmaxf(fabsf(v[j].z), fabsf(v[j].w))));
    }
#pragma unroll
    for (int off = 32; off; off >>= 1) amax = fmaxf(amax, __shfl_xor(amax, off));
    __shared__ float wred[4];
    __shared__ int   sred[4];
    if (lane == 0) wred[wv] = amax;
    __syncthreads();
    amax = fmaxf(fmaxf(wred[0], wred[1]), fmaxf(wred[2], wred[3]));
    const float inv = amax > 0.f ? 127.f / amax : 0.f;

    int lsum = 0;
    unsigned* orow = (unsigned*)(out + (size_t)row * K_DIM);
#pragma unroll
    for (int j = 0; j < 4; ++j) {
        int q0 = __float2int_rn(v[j].x * inv);
        int q1 = __float2int_rn(v[j].y * inv);
        int q2 = __float2int_rn(v[j].z * inv);
        int q3 = __float2int_rn(v[j].w * inv);
        lsum += q0 + q1 + q2 + q3;
        unsigned pk = (unsigned)(q0 & 0xFF) | ((unsigned)(q1 & 0xFF) << 8) |
                      ((unsigned)(q2 & 0xFF) << 16) | ((unsigned)(q3 & 0xFF) << 24);
        orow[t + 256 * j] = pk;
    }
#pragma unroll
    for (int off = 32; off; off >>= 1) lsum += __shfl_xor(lsum, off);
    if (lane == 0) sred[wv] = lsum;
    __syncthreads();
    if (t == 0) {
        rsum[row] = sred[0] + sred[1] + sred[2] + sred[3];
        srow[row] = amax > 0.f ? amax / 127.f : 1.f;
    }
}

// ---- prepass: W int32 -> i8 packed FRAGMENT-MAJOR ----
// W'[nt][kt][flane][16B]: nt=o/16, kt=k/64, flane=((k%64)/16)*16 + o%16.
// One block per output row o; thread t owns 16 consecutive int32 -> 16 bytes.
__global__ __launch_bounds__(256)
void pack_w_kernel(const int* __restrict__ q, char* __restrict__ out) {
    const int o = blockIdx.x;
    const int t = threadIdx.x;
    const int4* qp = (const int4*)(q + (size_t)o * K_DIM);
    int pk[4];
#pragma unroll
    for (int j = 0; j < 4; ++j) {
        int4 a = qp[t * 4 + j];
        pk[j] = (int)((unsigned)(a.x & 0xFF) | ((unsigned)(a.y & 0xFF) << 8) |
                      ((unsigned)(a.z & 0xFF) << 16) | ((unsigned)(a.w & 0xFF) << 24));
    }
    const int nt = o >> 4, r = o & 15;
    const int kt = t >> 2, j = t & 3;
    const size_t off = ((size_t)nt * NKT + kt) * 1024 + (size_t)(j * 16 + r) * 16;
    i32x4 w; w[0] = pk[0]; w[1] = pk[1]; w[2] = pk[2]; w[3] = pk[3];
    *(i32x4*)(out + off) = w;
}

// ---- 128x256 i8 GEMM: A via LDS ring-4 (serves x4 wave duplication on the
// 128B/cy LDS pipe), B direct from fragment-major packed global (1KB
// coalesced, no duplication, L1-served). Per CU per tile: L1 ~32KB (512cy),
// LDS read 64KB (~500cy), both << MFMA 1306cy -> MFMA-bound.
// 256 thr = 4 waves (all wr=0), per-wave out 128x64, acc i32x4[8][4].
// LDS = 4 slots x 8KB = 32 KiB -> 2 blocks/CU (desync co-tenant).
// A staging: gather-source global_load_lds (per-lane src from row-major Aq,
// m173), linear fragment-major dst -> ds_reads contiguous, conflict-free,
// NO swizzle. Sync: ONE barrier + vmcnt(2) per tile. Ledger: compiler's
// B-frag wait each tile leaves <=2 outstanding (the newest stage pair), so
// stage(u+2) is drained >=2 barriers before its readers; the tile-end
// vmcnt(2) (memory-clobber asm) pins this against reordering.
__global__ __launch_bounds__(256, 2)
void gemm_i8_kernel(const char* __restrict__ Aq, const char* __restrict__ Wp,
                    const float* __restrict__ srow, const int* __restrict__ rsum,
                    const float* __restrict__ wsc_p, const int* __restrict__ wzp_p,
                    const int* __restrict__ qb, const float* __restrict__ bsc_p,
                    const int* __restrict__ bzp_p, float* __restrict__ C) {
    __shared__ __align__(16) u8 ldsA[4 * 8192];   // 32 KiB

    // XCD-bijective swizzle + 8(bm)x4(bn) supertiles (nwg=2048, %8==0)
    const int nwg = gridDim.x;
    const int cpx = nwg >> 3;                 // 256
    const int bid = blockIdx.x;
    const int swz = (bid & 7) * cpx + (bid >> 3);
    const int st = swz >> 5, wi = swz & 31;   // 64 supertiles of 8x4
    const int bm = (st >> 2) * 8 + (wi >> 2); // 0..127
    const int bn = (st & 3) * 4 + (wi & 3);   // 0..15
    const int m0 = bm * 128, n0 = bn * 256;

    const int tid  = threadIdx.x;
    const int wv   = tid >> 6;    // 0..3 : wave col (64 N-cols each)
    const int lane = tid & 63;
    const int l15  = lane & 15;

    // A staging gather source: wave wv, instr i stages fragment f = wv*2+i;
    // lane l -> row m0 + f*16 + (l&15), k-offset (l>>4)*16 (+ u*64 per tile).
    const char* AgT = Aq + (size_t)(m0 + wv * 32 + l15) * K_DIM + ((lane >> 4) << 4);
    // B fragment base (packed W'): wave's 4 n-frags start at nt = bn*16 + wv*4
    const char* Wft = Wp + ((size_t)(bn * 16 + wv * 4) * NKT) * 1024 + lane * 16;

    i32x4 acc[8][4] = {};

    auto STAGE_A = [&](int ns, int u) {
#pragma unroll
        for (int i = 0; i < 2; ++i)
            __builtin_amdgcn_global_load_lds(
                (const AS1 void*)(AgT + (size_t)i * 16 * K_DIM + u * BK),
                (AS3 void*)(ldsA + ns * 8192 + (wv * 2 + i) * 1024), 16, 0, 0);
    };

    // ---- prologue: stage A tiles 0,1,2 (6 instr/wave) ----
    STAGE_A(0, 0);
    STAGE_A(1, 1);
    STAGE_A(2, 2);
    asm volatile("s_waitcnt vmcnt(4)" ::: "memory");   // tile 0 landed
    __builtin_amdgcn_s_barrier();

    for (int u = 0; u < NKT; ++u) {
        const u8* Asl = ldsA + (u & 3) * 8192;

        // B fragments: 4 coalesced 1KB loads from packed global (L1-served)
        i32x4 bfr[4];
#pragma unroll
        for (int ni = 0; ni < 4; ++ni)
            bfr[ni] = *(const i32x4*)(Wft + ((size_t)ni * NKT + u) * 1024);

        // stage A(u+3) into the slot tile u-1 vacated
        if (u + 3 < NKT) STAGE_A((u + 3) & 3, u + 3);

        // A fragments: 8 contiguous ds_read_b128 (conflict-free)
        i32x4 af[8];
#pragma unroll
        for (int mi = 0; mi < 8; ++mi)
            af[mi] = *(const i32x4*)(Asl + mi * 1024 + lane * 16);

        // MFMAs: compiler inserts fine-grained lgkm/vm waits per dependency
        __builtin_amdgcn_s_setprio(1);
#pragma unroll
        for (int mi = 0; mi < 8; ++mi)
#pragma unroll
            for (int ni = 0; ni < 4; ++ni)
                acc[mi][ni] = __builtin_amdgcn_mfma_i32_16x16x64_i8(
                    af[mi], bfr[ni], acc[mi][ni], 0, 0, 0);
        __builtin_amdgcn_s_setprio(0);

        // tile end: <=2 VMEM outstanding (newest stage pair) -> stage(u+2)
        // and older provably drained; barrier publishes cross-wave.
        asm volatile("s_waitcnt vmcnt(2)" ::: "memory");
        __builtin_amdgcn_s_barrier();
    }

    // ---- epilogue: dequant + zp correction + bias ----
    const float ws  = wsc_p[0];
    const float zpf = (float)wzp_p[0];
    const float bsc = bsc_p[0];
    const float bzp = (float)bzp_p[0];
    float bias_[4];
#pragma unroll
    for (int ni = 0; ni < 4; ++ni) {
        int col = n0 + wv * 64 + ni * 16 + l15;
        bias_[ni] = ((float)qb[col] - bzp) * bsc;
    }
#pragma unroll
    for (int mi = 0; mi < 8; ++mi) {
        int rbase = m0 + mi * 16 + (lane >> 4) * 4;
        float fs_[4], fc_[4];
#pragma unroll
        for (int i = 0; i < 4; ++i) {
            float sf = ws * srow[rbase + i];
            fs_[i] = sf;
            fc_[i] = -sf * zpf * (float)rsum[rbase + i];
        }
#pragma unroll
        for (int ni = 0; ni < 4; ++ni) {
            int col = n0 + wv * 64 + ni * 16 + l15;
#pragma unroll
            for (int i = 0; i < 4; ++i)
                C[(size_t)(rbase + i) * N_DIM + col] =
                    fs_[i] * (float)acc[mi][ni][i] + fc_[i] + bias_[ni];
        }
    }
}

// ---- fallback (only if ws too small): correct, slow ----
__global__ void gemm_fallback_kernel(const float* __restrict__ A, const int* __restrict__ Wq,
                                     const float* __restrict__ wsc_p, const int* __restrict__ wzp_p,
                                     const int* __restrict__ qb, const float* __restrict__ bsc_p,
                                     const int* __restrict__ bzp_p, float* __restrict__ C) {
    int m = blockIdx.y;
    int n = blockIdx.x * 256 + threadIdx.x;
    float zp = (float)wzp_p[0];
    float sc = wsc_p[0];
    __shared__ float Arow[512];
    float acc = 0.f;
    for (int k0 = 0; k0 < K_DIM; k0 += 512) {
        __syncthreads();
        for (int t = threadIdx.x; t < 512; t += 256)
            Arow[t] = A[(size_t)m * K_DIM + k0 + t];
        __syncthreads();
        const int4* wp = (const int4*)(Wq + (size_t)n * K_DIM + k0);
        for (int kk = 0; kk < 512; kk += 4) {
            int4 q = wp[kk >> 2];
            acc += Arow[kk]     * ((float)q.x - zp);
            acc += Arow[kk + 1] * ((float)q.y - zp);
            acc += Arow[kk + 2] * ((float)q.z - zp);
            acc += Arow[kk + 3] * ((float)q.w - zp);
        }
    }
    acc *= sc;
    acc += ((float)qb[n] - (float)bzp_p[0]) * bsc_p[0];
    C[(size_t)m * N_DIM + n] = acc;
}

extern "C" void kernel_launch(void* const* d_in, const int* in_sizes, int n_in,
                              void* d_out, int out_size, void* d_ws, size_t ws_size,
                              hipStream_t stream) {
    (void)in_sizes; (void)n_in; (void)out_size;
    const float* input = (const float*)d_in[0];
    const int*   qw    = (const int*)d_in[1];
    const float* wsc   = (const float*)d_in[2];
    const int*   wzp   = (const int*)d_in[3];
    const int*   qb    = (const int*)d_in[4];
    const float* bsc   = (const float*)d_in[5];
    const int*   bzp   = (const int*)d_in[6];
    float* out = (float*)d_out;

    size_t offA = 0;
    size_t offW = (size_t)M_DIM * K_DIM;                 // 64 MB (i8 row-major)
    size_t offS = offW + (size_t)N_DIM * K_DIM;          // +16 MB (W' packed)
    size_t offR = offS + (size_t)M_DIM * sizeof(float);  // +64 KB
    size_t need = offR + (size_t)M_DIM * sizeof(int);    // ~80.1 MB

    if (ws_size >= need) {
        char*  Aq = (char*)d_ws + offA;
        char*  Wq8 = (char*)d_ws + offW;
        float* S  = (float*)((char*)d_ws + offS);
        int*   R  = (int*)((char*)d_ws + offR);
        quant_a_kernel<<<M_DIM, 256, 0, stream>>>(input, Aq, S, R);
        pack_w_kernel<<<N_DIM, 256, 0, stream>>>(qw, Wq8);
        gemm_i8_kernel<<<(M_DIM / 128) * (N_DIM / 256), 256, 0, stream>>>(
            Aq, Wq8, S, R, wsc, wzp, qb, bsc, bzp, out);
    } else {
        dim3 grid(N_DIM / 256, M_DIM);
        gemm_fallback_kernel<<<grid, 256, 0, stream>>>(input, qw, wsc, wzp, qb, bsc, bzp, out);
    }
}